// Round 1
// baseline (336.348 us; speedup 1.0000x reference)
//
#include <hip/hip_runtime.h>

typedef __attribute__((ext_vector_type(8))) short bf16x8;
typedef __attribute__((ext_vector_type(4))) float f32x4;

#define HW 6400

__device__ inline unsigned short f2bf(float f) {
    unsigned u = __builtin_bit_cast(unsigned, f);
    unsigned r = (u + 0x7fffu + ((u >> 16) & 1u)) >> 16;
    return (unsigned short)r;
}

// ---------------- Projection kernel ----------------
// grid (100 pixel-tiles of 256, 4 co-tiles), block 256.
// co-tile 0 -> Q (64 ch), 1 -> K (64 ch), 2/3 -> V rows 0-63 / 64-127.
// Q,K stored [p][64] bf16 (p-major), V stored [c][HW] bf16 (c-major).
__global__ __launch_bounds__(256) void proj_kernel(
    const float* __restrict__ x,
    const float* __restrict__ Wq, const float* __restrict__ bq, const float* __restrict__ aq,
    const float* __restrict__ Wk, const float* __restrict__ bk, const float* __restrict__ ak,
    const float* __restrict__ Wv, const float* __restrict__ bv, const float* __restrict__ av,
    unsigned short* __restrict__ QT, unsigned short* __restrict__ KT,
    unsigned short* __restrict__ Vw)
{
    __shared__ float Wlds[64 * 128];   // 32 KB
    __shared__ float blds[64];
    __shared__ float slds;

    const int tid = threadIdx.x;
    const int ct = blockIdx.y;
    const float* Wsrc; const float* bsrc; const float* asrc;
    if (ct == 0)      { Wsrc = Wq;                bsrc = bq;             asrc = aq; }
    else if (ct == 1) { Wsrc = Wk;                bsrc = bk;             asrc = ak; }
    else              { Wsrc = Wv + (ct-2)*64*128; bsrc = bv + (ct-2)*64; asrc = av; }

    #pragma unroll
    for (int it = 0; it < 8; ++it) {
        int idx = it * 256 + tid;                  // 2048 float4 = 64x128 floats
        ((float4*)Wlds)[idx] = ((const float4*)Wsrc)[idx];
    }
    if (tid < 64) blds[tid] = bsrc[tid];
    if (tid == 0) slds = asrc[0];
    __syncthreads();
    const float slope = slds;

    const int p  = blockIdx.x * 256 + tid;         // 0..25599 (same n per block: 6400%256==0)
    const int n  = p / HW;
    const int pp = p - n * HW;
    const float* xp = x + (size_t)n * 128 * HW + pp;

    float acc[64];
    #pragma unroll
    for (int o = 0; o < 64; ++o) acc[o] = 0.f;

    for (int c = 0; c < 128; c += 4) {
        float x0 = xp[(size_t)(c + 0) * HW];
        float x1 = xp[(size_t)(c + 1) * HW];
        float x2 = xp[(size_t)(c + 2) * HW];
        float x3 = xp[(size_t)(c + 3) * HW];
        #pragma unroll
        for (int o = 0; o < 64; ++o) {
            float4 w = *(const float4*)&Wlds[o * 128 + c];
            acc[o] = fmaf(w.x, x0, acc[o]);
            acc[o] = fmaf(w.y, x1, acc[o]);
            acc[o] = fmaf(w.z, x2, acc[o]);
            acc[o] = fmaf(w.w, x3, acc[o]);
        }
    }

    if (ct < 2) {
        unsigned short* dst = (ct == 0 ? QT : KT) + (size_t)p * 64;
        #pragma unroll
        for (int v8 = 0; v8 < 8; ++v8) {
            bf16x8 pk;
            #pragma unroll
            for (int e = 0; e < 8; ++e) {
                int o = v8 * 8 + e;
                float y = acc[o] + blds[o];
                y = (y >= 0.f) ? y : slope * y;
                pk[e] = (short)f2bf(y);
            }
            *(bf16x8*)(dst + v8 * 8) = pk;         // 128 B contiguous per thread
        }
    } else {
        const int co_base = (ct - 2) * 64;
        #pragma unroll
        for (int o = 0; o < 64; ++o) {
            float y = acc[o] + blds[o];
            y = (y >= 0.f) ? y : slope * y;
            Vw[((size_t)n * 128 + co_base + o) * HW + pp] = f2bf(y);  // lane-coalesced per o
        }
    }
}

// ---------------- Flash attention kernel ----------------
// grid 400 (= 4 batches x 100 i-tiles of 64 rows), block 256 (4 waves, 16 rows/wave).
// S = Q^T K via mfma(Qfrag, Kfrag); online softmax per wave (rows live in lane
// groups of 16, 4 rows per group via acc regs); P staged to per-wave LDS;
// O accumulated TRANSPOSED: O^T = V * P^T so the epilogue store is coalesced.
__global__ __launch_bounds__(256) void attn_kernel(
    const unsigned short* __restrict__ QT,
    const unsigned short* __restrict__ KT,
    const unsigned short* __restrict__ Vw,
    float* __restrict__ out)
{
    __shared__ char lds[32768];
    char* Klds = lds;                 // [64 j][64 c] bf16, XOR-swizzled, 8 KB
    char* Vlds = lds + 8192;          // [128 c][64 j] bf16, XOR-swizzled, 16 KB
    char* Plds = lds + 24576;         // 4 waves x [16 i][64 j] bf16, swizzled, 8 KB

    const int tid  = threadIdx.x;
    const int lane = tid & 63;
    const int w    = tid >> 6;
    const int l15  = lane & 15;
    const int lhi  = lane >> 4;

    const int bid = blockIdx.x;
    const int n   = bid / 100;
    const int i0  = (bid - n * 100) * 64;

    const char* Kb = (const char*)(KT + (size_t)n * HW * 64);
    const char* Vb = (const char*)(Vw + (size_t)n * 128 * HW);

    // Q fragments for this wave's 16 rows (row = i0 + w*16 + l15), k = c
    const unsigned short* qptr = QT + ((size_t)n * HW + i0 + w * 16 + l15) * 64 + lhi * 8;
    bf16x8 qf0 = *(const bf16x8*)qptr;
    bf16x8 qf1 = *(const bf16x8*)(qptr + 32);

    const f32x4 zero4 = {0.f, 0.f, 0.f, 0.f};
    f32x4 o_acc[8];
    #pragma unroll
    for (int cb = 0; cb < 8; ++cb) o_acc[cb] = zero4;
    float m_r[4] = {-3e38f, -3e38f, -3e38f, -3e38f};
    float l_r[4] = {0.f, 0.f, 0.f, 0.f};

    char* Pw = Plds + w * 2048;
    const float L2E = 1.44269504088896f;

    for (int jt = 0; jt < 100; ++jt) {
        __syncthreads();   // previous tile's LDS reads done before overwrite
        // stage K tile: 64 rows (j) x 128 B, 512 x 16B chunks
        #pragma unroll
        for (int s = 0; s < 2; ++s) {
            int chunk = s * 256 + tid;
            int row = chunk >> 3, cc = chunk & 7;
            float4 d = *(const float4*)(Kb + (size_t)(jt * 64 + row) * 128 + cc * 16);
            *(float4*)(Klds + row * 128 + ((cc * 16) ^ ((row & 7) << 4))) = d;
        }
        // stage V tile: 128 rows (c) x 128 B, 1024 x 16B chunks
        #pragma unroll
        for (int s = 0; s < 4; ++s) {
            int chunk = s * 256 + tid;
            int c = chunk >> 3, cc = chunk & 7;
            float4 d = *(const float4*)(Vb + (size_t)c * 12800 + (size_t)jt * 128 + cc * 16);
            *(float4*)(Vlds + c * 128 + ((cc * 16) ^ ((c & 7) << 4))) = d;
        }
        __syncthreads();

        // ---- S = Q^T K  (4 j-subtiles of 16, K-dim = 64 channels = 2 MFMAs) ----
        f32x4 s_acc[4];
        #pragma unroll
        for (int js = 0; js < 4; ++js) {
            int row = js * 16 + l15;
            bf16x8 b0 = *(const bf16x8*)(Klds + row * 128 + (((0 + lhi) * 16) ^ ((row & 7) << 4)));
            bf16x8 b1 = *(const bf16x8*)(Klds + row * 128 + (((4 + lhi) * 16) ^ ((row & 7) << 4)));
            f32x4 sa = zero4;
            sa = __builtin_amdgcn_mfma_f32_16x16x32_bf16(qf0, b0, sa, 0, 0, 0);
            sa = __builtin_amdgcn_mfma_f32_16x16x32_bf16(qf1, b1, sa, 0, 0, 0);
            s_acc[js] = sa;
        }

        // ---- online softmax (rows g*4+r live in lane-group g, reg r) ----
        float alpha[4], rs[4];
        #pragma unroll
        for (int r = 0; r < 4; ++r) {
            float v = fmaxf(fmaxf(s_acc[0][r], s_acc[1][r]), fmaxf(s_acc[2][r], s_acc[3][r]));
            v = fmaxf(v, __shfl_xor(v, 1, 64));
            v = fmaxf(v, __shfl_xor(v, 2, 64));
            v = fmaxf(v, __shfl_xor(v, 4, 64));
            v = fmaxf(v, __shfl_xor(v, 8, 64));
            float mnew = fmaxf(m_r[r], v);
            alpha[r] = exp2f((m_r[r] - mnew) * L2E);
            m_r[r] = mnew;
            rs[r] = 0.f;
        }
        // P = exp(S - m): write bf16 to per-wave LDS, accumulate row sums
        #pragma unroll
        for (int js = 0; js < 4; ++js) {
            #pragma unroll
            for (int r = 0; r < 4; ++r) {
                float pv = exp2f((s_acc[js][r] - m_r[r]) * L2E);
                unsigned short pb = f2bf(pv);
                rs[r] += __builtin_bit_cast(float, (unsigned)pb << 16);  // sum the rounded value
                int i = lhi * 4 + r;
                int j = js * 16 + l15;
                *(unsigned short*)(Pw + ((i * 128 + j * 2) ^ ((i & 7) << 4))) = pb;
            }
        }
        #pragma unroll
        for (int r = 0; r < 4; ++r) {
            float v = rs[r];
            v += __shfl_xor(v, 1, 64);
            v += __shfl_xor(v, 2, 64);
            v += __shfl_xor(v, 4, 64);
            v += __shfl_xor(v, 8, 64);
            l_r[r] = l_r[r] * alpha[r] + v;
        }

        // rescale O^T: factor depends on i = l15 -> broadcast from row-group layout
        {
            int srcl = (l15 >> 2) << 4;
            float a0 = __shfl(alpha[0], srcl, 64);
            float a1 = __shfl(alpha[1], srcl, 64);
            float a2 = __shfl(alpha[2], srcl, 64);
            float a3 = __shfl(alpha[3], srcl, 64);
            int rr = l15 & 3;
            float fa = (rr == 0) ? a0 : (rr == 1) ? a1 : (rr == 2) ? a2 : a3;
            #pragma unroll
            for (int cb = 0; cb < 8; ++cb) o_acc[cb] *= fa;
        }

        // ---- O^T += V * P^T  (8 c-blocks x 2 j-chunks of 32) ----
        #pragma unroll
        for (int jc = 0; jc < 2; ++jc) {
            bf16x8 pfrag = *(const bf16x8*)(Pw + ((l15 * 128 + (jc * 4 + lhi) * 16) ^ ((l15 & 7) << 4)));
            #pragma unroll
            for (int cb = 0; cb < 8; ++cb) {
                int row = cb * 16 + l15;
                bf16x8 vfrag = *(const bf16x8*)(Vlds + row * 128 + (((jc * 4 + lhi) * 16) ^ ((row & 7) << 4)));
                o_acc[cb] = __builtin_amdgcn_mfma_f32_16x16x32_bf16(vfrag, pfrag, o_acc[cb], 0, 0, 0);
            }
        }
    }

    // ---- epilogue: divide by row sum, coalesced store of O^T ----
    int srcl = (l15 >> 2) << 4;
    float t0 = __shfl(l_r[0], srcl, 64);
    float t1 = __shfl(l_r[1], srcl, 64);
    float t2 = __shfl(l_r[2], srcl, 64);
    float t3 = __shfl(l_r[3], srcl, 64);
    int rr = l15 & 3;
    float lsum = (rr == 0) ? t0 : (rr == 1) ? t1 : (rr == 2) ? t2 : t3;
    float linv = 1.f / lsum;

    float* ob = out + (size_t)n * 128 * HW + i0 + w * 16 + l15;
    #pragma unroll
    for (int cb = 0; cb < 8; ++cb) {
        #pragma unroll
        for (int r = 0; r < 4; ++r) {
            int c = cb * 16 + lhi * 4 + r;
            ob[(size_t)c * HW] = o_acc[cb][r] * linv;
        }
    }
}

extern "C" void kernel_launch(void* const* d_in, const int* in_sizes, int n_in,
                              void* d_out, int out_size, void* d_ws, size_t ws_size,
                              hipStream_t stream) {
    const float* x  = (const float*)d_in[0];
    const float* Wq = (const float*)d_in[1];
    const float* bq = (const float*)d_in[2];
    const float* aq = (const float*)d_in[3];
    const float* Wk = (const float*)d_in[4];
    const float* bk = (const float*)d_in[5];
    const float* ak = (const float*)d_in[6];
    const float* Wv = (const float*)d_in[7];
    const float* bv = (const float*)d_in[8];
    const float* av = (const float*)d_in[9];

    unsigned short* QT = (unsigned short*)d_ws;        // [25600][64] bf16
    unsigned short* KT = QT + (size_t)25600 * 64;      // [25600][64] bf16
    unsigned short* Vw = KT + (size_t)25600 * 64;      // [4][128][6400] bf16

    proj_kernel<<<dim3(100, 4), 256, 0, stream>>>(x, Wq, bq, aq, Wk, bk, ak, Wv, bv, av,
                                                  QT, KT, Vw);
    attn_kernel<<<dim3(400), 256, 0, stream>>>(QT, KT, Vw, (float*)d_out);
}

// Round 2
// 315.925 us; speedup vs baseline: 1.0646x; 1.0646x over previous
//
#include <hip/hip_runtime.h>

typedef __attribute__((ext_vector_type(8)))  short bf16x8;
typedef __attribute__((ext_vector_type(4)))  float f32x4;
typedef __attribute__((ext_vector_type(16))) float f32x16;

#define HW 6400
#define L2E 1.44269504088896f
#define DEFER_THR 8.0f   // in log2 units (Q pre-scaled by L2E): P <= 2^8

__device__ inline unsigned short f2bf(float f) {
    unsigned u = __builtin_bit_cast(unsigned, f);
    unsigned r = (u + 0x7fffu + ((u >> 16) & 1u)) >> 16;
    return (unsigned short)r;
}

__device__ inline unsigned cvt_pk_bf16(float lo, float hi) {
    unsigned r;
    asm("v_cvt_pk_bf16_f32 %0, %1, %2" : "=v"(r) : "v"(lo), "v"(hi));
    return r;
}

// ---------------- Projection kernel ----------------
// grid (200 pixel-tiles of 128, 4 co-tiles), block 128.
// ct 0 -> Q (64 ch, pre-scaled by log2(e)), 1 -> K (64), 2/3 -> V[0:64]/V[64:128].
// Q,K stored [p][64] bf16 (p-major), V stored [c][HW] bf16 (c-major).
__global__ __launch_bounds__(128) void proj_kernel(
    const float* __restrict__ x,
    const float* __restrict__ Wq, const float* __restrict__ bq, const float* __restrict__ aq,
    const float* __restrict__ Wk, const float* __restrict__ bk, const float* __restrict__ ak,
    const float* __restrict__ Wv, const float* __restrict__ bv, const float* __restrict__ av,
    unsigned short* __restrict__ QT, unsigned short* __restrict__ KT,
    unsigned short* __restrict__ Vw)
{
    __shared__ float Wlds[64 * 128];   // 32 KB
    __shared__ float blds[64];
    __shared__ float slds;

    const int tid = threadIdx.x;
    const int ct = blockIdx.y;
    const float* Wsrc; const float* bsrc; const float* asrc;
    if (ct == 0)      { Wsrc = Wq;                 bsrc = bq;              asrc = aq; }
    else if (ct == 1) { Wsrc = Wk;                 bsrc = bk;              asrc = ak; }
    else              { Wsrc = Wv + (ct-2)*64*128; bsrc = bv + (ct-2)*64;  asrc = av; }

    #pragma unroll
    for (int it = 0; it < 16; ++it) {
        int idx = it * 128 + tid;                  // 2048 float4 = 64x128 floats
        ((float4*)Wlds)[idx] = ((const float4*)Wsrc)[idx];
    }
    if (tid < 64) blds[tid] = bsrc[tid];
    if (tid == 0) slds = asrc[0];
    __syncthreads();
    const float slope = slds;
    const float oscale = (ct == 0) ? L2E : 1.0f;   // fold log2(e) into Q

    const int p  = blockIdx.x * 128 + tid;         // 6400 % 128 == 0 -> same n per block
    const int n  = p / HW;
    const int pp = p - n * HW;
    const float* xp = x + (size_t)n * 128 * HW + pp;

    float acc[64];
    #pragma unroll
    for (int o = 0; o < 64; ++o) acc[o] = 0.f;

    for (int c = 0; c < 128; c += 4) {
        float x0 = xp[(size_t)(c + 0) * HW];
        float x1 = xp[(size_t)(c + 1) * HW];
        float x2 = xp[(size_t)(c + 2) * HW];
        float x3 = xp[(size_t)(c + 3) * HW];
        #pragma unroll
        for (int o = 0; o < 64; ++o) {
            float4 w = *(const float4*)&Wlds[o * 128 + c];
            acc[o] = fmaf(w.x, x0, acc[o]);
            acc[o] = fmaf(w.y, x1, acc[o]);
            acc[o] = fmaf(w.z, x2, acc[o]);
            acc[o] = fmaf(w.w, x3, acc[o]);
        }
    }

    if (ct < 2) {
        unsigned short* dst = (ct == 0 ? QT : KT) + (size_t)p * 64;
        #pragma unroll
        for (int v8 = 0; v8 < 8; ++v8) {
            bf16x8 pk;
            #pragma unroll
            for (int e = 0; e < 8; ++e) {
                int o = v8 * 8 + e;
                float y = acc[o] + blds[o];
                y = (y >= 0.f) ? y : slope * y;
                pk[e] = (short)f2bf(y * oscale);
            }
            *(bf16x8*)(dst + v8 * 8) = pk;
        }
    } else {
        const int co_base = (ct - 2) * 64;
        #pragma unroll
        for (int o = 0; o < 64; ++o) {
            float y = acc[o] + blds[o];
            y = (y >= 0.f) ? y : slope * y;
            Vw[((size_t)n * 128 + co_base + o) * HW + pp] = f2bf(y);
        }
    }
}

// ---------------- Flash attention kernel (swapped-operand, 32x32 MFMA) ----------------
// block 128 (2 waves x 32 query rows), grid = 4n * 100 it * jsplit.
// S^T = mfma(K, Q): lane owns row i = lane&31 -> in-lane softmax, per-lane alpha.
// P packed to bf16 in-register via cvt_pk + permlane32_swap (no P LDS).
// O accumulated transposed (O^T = V P^T), i stays lane-local -> shuffle-free epilogue.
__global__ __launch_bounds__(128, 2) void attn_kernel(
    const unsigned short* __restrict__ QT,
    const unsigned short* __restrict__ KT,
    const unsigned short* __restrict__ Vw,
    float* __restrict__ out,
    float* __restrict__ Opart, float* __restrict__ Mpart, float* __restrict__ Lpart,
    int jsplit, int NT)
{
    __shared__ char lds[24576];
    char* Klds = lds;                 // [64 j][64 c] bf16, XOR-swizzled, 8 KB
    char* Vlds = lds + 8192;          // [128 c][64 j] bf16, XOR-swizzled, 16 KB

    const int tid  = threadIdx.x;
    const int lane = tid & 63;
    const int w    = tid >> 6;
    const int l31  = lane & 31;
    const int h    = lane >> 5;

    const int bid   = blockIdx.x;
    const int per_n = 100 * jsplit;
    const int n     = bid / per_n;
    const int rem   = bid - n * per_n;
    const int it    = rem / jsplit;
    const int js    = rem - it * jsplit;
    const int i0    = it * 64;
    const int jt0   = js * NT;

    const int row = i0 + w * 32 + l31;          // this lane's query row
    const unsigned short* qbase = QT + ((size_t)n * HW + row) * 64;
    bf16x8 qf0 = *(const bf16x8*)(qbase + 0 * 16 + h * 8);
    bf16x8 qf1 = *(const bf16x8*)(qbase + 1 * 16 + h * 8);
    bf16x8 qf2 = *(const bf16x8*)(qbase + 2 * 16 + h * 8);
    bf16x8 qf3 = *(const bf16x8*)(qbase + 3 * 16 + h * 8);

    const char* Kb = (const char*)(KT + (size_t)n * HW * 64);
    const char* Vb = (const char*)(Vw + (size_t)n * 128 * HW);

    const f32x16 z16 = {0,0,0,0,0,0,0,0,0,0,0,0,0,0,0,0};
    f32x16 o_acc[4];
    #pragma unroll
    for (int cb = 0; cb < 4; ++cb) o_acc[cb] = z16;
    float m = -3e38f, lsum = 0.f;

    for (int t = 0; t < NT; ++t) {
        const int jt = jt0 + t;
        __syncthreads();
        // stage K tile: 64 rows x 128 B = 512 chunks of 16 B
        #pragma unroll
        for (int s = 0; s < 4; ++s) {
            int chunk = s * 128 + tid;
            int r = chunk >> 3, cc = chunk & 7;
            float4 d = *(const float4*)(Kb + (size_t)(jt * 64 + r) * 128 + cc * 16);
            *(float4*)(Klds + r * 128 + ((cc * 16) ^ ((r & 7) << 4))) = d;
        }
        // stage V tile: 128 rows x 128 B = 1024 chunks
        #pragma unroll
        for (int s = 0; s < 8; ++s) {
            int chunk = s * 128 + tid;
            int c = chunk >> 3, cc = chunk & 7;
            float4 d = *(const float4*)(Vb + (size_t)c * (HW * 2) + (size_t)jt * 128 + cc * 16);
            *(float4*)(Vlds + c * 128 + ((cc * 16) ^ ((c & 7) << 4))) = d;
        }
        __syncthreads();

        // ---- S^T = K * Q  (two 32-j subtiles, K-dim 64 = 4 MFMAs each) ----
        f32x16 s0 = z16, s1 = z16;
        #pragma unroll
        for (int kc = 0; kc < 4; ++kc) {
            const int cidx = (2 * kc + h) * 16;
            bf16x8 kf0 = *(const bf16x8*)(Klds + l31 * 128        + (cidx ^ ((l31 & 7) << 4)));
            bf16x8 kf1 = *(const bf16x8*)(Klds + (32 + l31) * 128 + (cidx ^ ((l31 & 7) << 4)));
            bf16x8 qf = (kc == 0) ? qf0 : (kc == 1) ? qf1 : (kc == 2) ? qf2 : qf3;
            s0 = __builtin_amdgcn_mfma_f32_32x32x16_bf16(kf0, qf, s0, 0, 0, 0);
            s1 = __builtin_amdgcn_mfma_f32_32x32x16_bf16(kf1, qf, s1, 0, 0, 0);
        }

        // ---- in-lane online softmax (lane owns row i = l31; halves share via xor-32) ----
        float rmax = s0[0];
        #pragma unroll
        for (int r = 1; r < 16; ++r) rmax = fmaxf(rmax, s0[r]);
        #pragma unroll
        for (int r = 0; r < 16; ++r) rmax = fmaxf(rmax, s1[r]);
        rmax = fmaxf(rmax, __shfl_xor(rmax, 32, 64));

        if (__any(rmax > m + DEFER_THR)) {         // defer-max: skip rescale on small growth
            float mnew = fmaxf(m, rmax);
            float alpha = exp2f(m - mnew);
            lsum *= alpha;
            #pragma unroll
            for (int cb = 0; cb < 4; ++cb)
                #pragma unroll
                for (int r = 0; r < 16; ++r) o_acc[cb][r] *= alpha;
            m = mnew;
        }

        float rs = 0.f;
        #pragma unroll
        for (int r = 0; r < 16; ++r) { s0[r] = exp2f(s0[r] - m); rs += s0[r]; }
        #pragma unroll
        for (int r = 0; r < 16; ++r) { s1[r] = exp2f(s1[r] - m); rs += s1[r]; }
        rs += __shfl_xor(rs, 32, 64);
        lsum += rs;

        // ---- pack P^T B-fragments in-register (cvt_pk + permlane32_swap) ----
        bf16x8 pf[4];
        #pragma unroll
        for (int kb = 0; kb < 4; ++kb) {
            f32x16 sv = (kb < 2) ? s0 : s1;
            const int b = (kb & 1) * 8;
            unsigned w0 = cvt_pk_bf16(sv[b + 0], sv[b + 1]);
            unsigned w1 = cvt_pk_bf16(sv[b + 2], sv[b + 3]);
            unsigned w2 = cvt_pk_bf16(sv[b + 4], sv[b + 5]);
            unsigned w3 = cvt_pk_bf16(sv[b + 6], sv[b + 7]);
            asm("v_permlane32_swap_b32 %0, %1" : "+v"(w0), "+v"(w2));
            asm("v_permlane32_swap_b32 %0, %1" : "+v"(w1), "+v"(w3));
            union { unsigned u[4]; bf16x8 v; } uu;
            uu.u[0] = w0; uu.u[1] = w1; uu.u[2] = w2; uu.u[3] = w3;
            pf[kb] = uu.v;
        }

        // ---- O^T += V * P^T  (4 j-chunks of 16 x 4 c-blocks of 32) ----
        #pragma unroll
        for (int kb = 0; kb < 4; ++kb) {
            const int jidx = (2 * kb + h) * 16;
            #pragma unroll
            for (int cb = 0; cb < 4; ++cb) {
                const int crow = cb * 32 + l31;
                bf16x8 vf = *(const bf16x8*)(Vlds + crow * 128 + (jidx ^ ((crow & 7) << 4)));
                o_acc[cb] = __builtin_amdgcn_mfma_f32_32x32x16_bf16(vf, pf[kb], o_acc[cb], 0, 0, 0);
            }
        }
    }

    // ---- epilogue: i = l31 is lane-local -> coalesced stores, no shuffles ----
    if (Opart != nullptr) {
        float* Ob = Opart + ((size_t)(js * 4 + n) * 128) * HW + row;
        #pragma unroll
        for (int cb = 0; cb < 4; ++cb)
            #pragma unroll
            for (int r = 0; r < 16; ++r) {
                int c = cb * 32 + (r & 3) + 8 * (r >> 2) + 4 * h;
                Ob[(size_t)c * HW] = o_acc[cb][r];
            }
        if (h == 0) {
            Mpart[(size_t)(js * 4 + n) * HW + row] = m;
            Lpart[(size_t)(js * 4 + n) * HW + row] = lsum;
        }
    } else {
        float inv = 1.f / lsum;
        float* ob = out + (size_t)n * 128 * HW + row;
        #pragma unroll
        for (int cb = 0; cb < 4; ++cb)
            #pragma unroll
            for (int r = 0; r < 16; ++r) {
                int c = cb * 32 + (r & 3) + 8 * (r >> 2) + 4 * h;
                ob[(size_t)c * HW] = o_acc[cb][r] * inv;
            }
    }
}

// ---------------- Combine kernel (jsplit = 4 hardcoded) ----------------
// grid 400: (4 n) x (4 c-quarters) x (25 i-chunks of 256), block 256.
__global__ __launch_bounds__(256) void combine_kernel(
    const float* __restrict__ Opart, const float* __restrict__ Mpart,
    const float* __restrict__ Lpart, float* __restrict__ out)
{
    const int b = blockIdx.x;
    const int n = b / 100;
    const int rem = b - n * 100;
    const int cq = rem / 25;
    const int ic = rem - cq * 25;
    const int i = ic * 256 + threadIdx.x;

    float mj[4], wj[4];
    #pragma unroll
    for (int js = 0; js < 4; ++js) mj[js] = Mpart[(size_t)(js * 4 + n) * HW + i];
    float M = fmaxf(fmaxf(mj[0], mj[1]), fmaxf(mj[2], mj[3]));
    float L = 0.f;
    #pragma unroll
    for (int js = 0; js < 4; ++js) {
        wj[js] = exp2f(mj[js] - M);
        L += Lpart[(size_t)(js * 4 + n) * HW + i] * wj[js];
    }
    const float inv = 1.f / L;

    for (int c = cq * 32; c < cq * 32 + 32; ++c) {
        float acc = 0.f;
        #pragma unroll
        for (int js = 0; js < 4; ++js)
            acc += Opart[((size_t)(js * 4 + n) * 128 + c) * HW + i] * wj[js];
        out[((size_t)n * 128 + c) * HW + i] = acc * inv;
    }
}

extern "C" void kernel_launch(void* const* d_in, const int* in_sizes, int n_in,
                              void* d_out, int out_size, void* d_ws, size_t ws_size,
                              hipStream_t stream) {
    const float* x  = (const float*)d_in[0];
    const float* Wq = (const float*)d_in[1];
    const float* bq = (const float*)d_in[2];
    const float* aq = (const float*)d_in[3];
    const float* Wk = (const float*)d_in[4];
    const float* bk = (const float*)d_in[5];
    const float* ak = (const float*)d_in[6];
    const float* Wv = (const float*)d_in[7];
    const float* bv = (const float*)d_in[8];
    const float* av = (const float*)d_in[9];

    char* w = (char*)d_ws;
    unsigned short* QT = (unsigned short*)w;                       // 25600*64*2 = 3,276,800 B
    unsigned short* KT = (unsigned short*)(w + 3276800);           // 3,276,800 B
    unsigned short* Vw = (unsigned short*)(w + 6553600);           // 4*128*6400*2 = 6,553,600 B
    const size_t base = 13107200;
    float* Opart = (float*)(w + base);                              // 4*4*128*6400*4 = 52,428,800 B
    float* Mpart = (float*)(w + base + 52428800);                   // 409,600 B
    float* Lpart = (float*)(w + base + 52428800 + 409600);          // 409,600 B
    const size_t need = base + 52428800 + 2 * 409600;

    proj_kernel<<<dim3(200, 4), 128, 0, stream>>>(x, Wq, bq, aq, Wk, bk, ak, Wv, bv, av,
                                                  QT, KT, Vw);

    if (ws_size >= need) {
        const int jsplit = 4, NT = 25;
        attn_kernel<<<dim3(4 * 100 * jsplit), 128, 0, stream>>>(QT, KT, Vw, (float*)d_out,
                                                                Opart, Mpart, Lpart, jsplit, NT);
        combine_kernel<<<dim3(400), 256, 0, stream>>>(Opart, Mpart, Lpart, (float*)d_out);
    } else {
        attn_kernel<<<dim3(400), 128, 0, stream>>>(QT, KT, Vw, (float*)d_out,
                                                   nullptr, nullptr, nullptr, 1, 100);
    }
}

// Round 3
// 134.101 us; speedup vs baseline: 2.5082x; 2.3559x over previous
//
#include <hip/hip_runtime.h>

typedef __attribute__((ext_vector_type(8)))  short bf16x8;
typedef __attribute__((ext_vector_type(16))) float f32x16;
typedef unsigned int u32;
typedef unsigned short u16;

#define HW 6400
#define L2E 1.44269504088896f
#define DEFER_THR 8.0f

__device__ inline u16 f2bf(float f) {
    u32 u = __builtin_bit_cast(u32, f);
    u32 r = (u + 0x7fffu + ((u >> 16) & 1u)) >> 16;
    return (u16)r;
}
__device__ inline u32 cvt_pk_bf16(float lo, float hi) {
    u32 r;
    asm("v_cvt_pk_bf16_f32 %0, %1, %2" : "=v"(r) : "v"(lo), "v"(hi));
    return r;
}
__device__ inline void gload_lds16(const void* g, void* l) {
    __builtin_amdgcn_global_load_lds(
        (const __attribute__((address_space(1))) u32*)g,
        (__attribute__((address_space(3))) u32*)l, 16, 0, 0);
}

// ---------------- Projection kernel (MFMA) ----------------
// grid 400 = 4n x 100 p-tiles of 64, block 256 = 4 waves.
// wave 0 -> Q (64 ch, x log2e, stored c-major), wave 1 -> K (stored p-major via
// LDS transpose), waves 2/3 -> V[0:64]/V[64:128] (c-major).
__global__ __launch_bounds__(256) void proj_kernel(
    const float* __restrict__ x,
    const float* __restrict__ Wq, const float* __restrict__ bq, const float* __restrict__ aq,
    const float* __restrict__ Wk, const float* __restrict__ bk, const float* __restrict__ ak,
    const float* __restrict__ Wv, const float* __restrict__ bv, const float* __restrict__ av,
    u16* __restrict__ QTc, u16* __restrict__ KT, u16* __restrict__ Vw)
{
    __shared__ char xs[64 * 272];      // x tile, [64 p][128 ch bf16 + pad], 272 B rows
    __shared__ char ktr[64 * 144];     // K transpose buffer [64 p][64 ch bf16 + pad]

    const int tid  = threadIdx.x;
    const int lane = tid & 63;
    const int w    = tid >> 6;
    const int l31  = lane & 31;
    const int h    = lane >> 5;

    const int blk = blockIdx.x;        // 4n * 100
    const int n   = blk / 100;
    const int pt  = blk - n * 100;
    const int p0  = pt * 64;

    // ---- stage x tile [128 c][64 p] f32 -> xs [p][c] bf16 ----
    const float* xb = x + (size_t)n * 128 * HW + p0;
    #pragma unroll
    for (int it = 0; it < 8; ++it) {
        int idx = it * 256 + tid;      // 2048 float4 = 128 c x 16 p-quads
        int c = idx >> 4, p4 = (idx & 15) * 4;
        float4 d = *(const float4*)(xb + (size_t)c * HW + p4);
        *(u16*)(xs + (p4 + 0) * 272 + c * 2) = f2bf(d.x);
        *(u16*)(xs + (p4 + 1) * 272 + c * 2) = f2bf(d.y);
        *(u16*)(xs + (p4 + 2) * 272 + c * 2) = f2bf(d.z);
        *(u16*)(xs + (p4 + 3) * 272 + c * 2) = f2bf(d.w);
    }
    __syncthreads();

    const float* Wsrc; const float* bsrc; float slope; float osc = 1.0f;
    if (w == 0)      { Wsrc = Wq;                 bsrc = bq;             slope = aq[0]; osc = L2E; }
    else if (w == 1) { Wsrc = Wk;                 bsrc = bk;             slope = ak[0]; }
    else             { Wsrc = Wv + (w-2)*64*128;  bsrc = bv + (w-2)*64;  slope = av[0]; }

    // ---- W A-frags in registers: lane row ch = cb*32+l31, k-chunk kc*16+h*8 ----
    bf16x8 wf[2][8];
    #pragma unroll
    for (int cb = 0; cb < 2; ++cb)
        #pragma unroll
        for (int kc = 0; kc < 8; ++kc) {
            const float* ws = Wsrc + (cb * 32 + l31) * 128 + kc * 16 + h * 8;
            float4 a = *(const float4*)ws;
            float4 b = *(const float4*)(ws + 4);
            union { u32 u[4]; bf16x8 v; } uu;
            uu.u[0] = cvt_pk_bf16(a.x, a.y);
            uu.u[1] = cvt_pk_bf16(a.z, a.w);
            uu.u[2] = cvt_pk_bf16(b.x, b.y);
            uu.u[3] = cvt_pk_bf16(b.z, b.w);
            wf[cb][kc] = uu.v;
        }

    f32x16 acc[2][2] = {};
    #pragma unroll
    for (int kc = 0; kc < 8; ++kc) {
        bf16x8 xb0 = *(const bf16x8*)(xs + (l31)      * 272 + kc * 32 + h * 16);
        bf16x8 xb1 = *(const bf16x8*)(xs + (l31 + 32) * 272 + kc * 32 + h * 16);
        acc[0][0] = __builtin_amdgcn_mfma_f32_32x32x16_bf16(wf[0][kc], xb0, acc[0][0], 0, 0, 0);
        acc[0][1] = __builtin_amdgcn_mfma_f32_32x32x16_bf16(wf[0][kc], xb1, acc[0][1], 0, 0, 0);
        acc[1][0] = __builtin_amdgcn_mfma_f32_32x32x16_bf16(wf[1][kc], xb0, acc[1][0], 0, 0, 0);
        acc[1][1] = __builtin_amdgcn_mfma_f32_32x32x16_bf16(wf[1][kc], xb1, acc[1][1], 0, 0, 0);
    }

    // D layout: col p = l31 (+pb*32), row ch = cb*32 + (r&3)+8*(r>>2)+4h
    if (w != 1) {
        u16* dst = (w == 0) ? (QTc + (size_t)n * 64 * HW)
                            : (Vw + ((size_t)n * 128 + (size_t)(w - 2) * 64) * HW);
        #pragma unroll
        for (int cb = 0; cb < 2; ++cb)
            #pragma unroll
            for (int pb = 0; pb < 2; ++pb)
                #pragma unroll
                for (int r = 0; r < 16; ++r) {
                    int ch = cb * 32 + (r & 3) + 8 * (r >> 2) + 4 * h;
                    float y = acc[cb][pb][r] + bsrc[ch];
                    y = (y >= 0.f) ? y : slope * y;
                    dst[(size_t)ch * HW + p0 + pb * 32 + l31] = f2bf(y * osc);
                }
    } else {
        // K: bias+PReLU, pack ch-pairs, transpose through LDS, store p-major
        #pragma unroll
        for (int cb = 0; cb < 2; ++cb)
            #pragma unroll
            for (int pb = 0; pb < 2; ++pb)
                #pragma unroll
                for (int rp = 0; rp < 8; ++rp) {
                    int r0 = rp * 2;
                    int ch = cb * 32 + (r0 & 3) + 8 * (r0 >> 2) + 4 * h;
                    float y0 = acc[cb][pb][r0]     + bsrc[ch];
                    float y1 = acc[cb][pb][r0 + 1] + bsrc[ch + 1];
                    y0 = (y0 >= 0.f) ? y0 : slope * y0;
                    y1 = (y1 >= 0.f) ? y1 : slope * y1;
                    *(u32*)(ktr + (pb * 32 + l31) * 144 + ch * 2) = cvt_pk_bf16(y0, y1);
                }
        // readback rows p, store coalesced 128B rows (single wave: lgkmcnt dep handled)
        #pragma unroll
        for (int i8 = 0; i8 < 8; ++i8) {
            int p = i8 * 8 + (lane >> 3);
            bf16x8 d = *(const bf16x8*)(ktr + p * 144 + (lane & 7) * 16);
            *(bf16x8*)(KT + ((size_t)n * HW + p0 + p) * 64 + (lane & 7) * 8) = d;
        }
    }
}

// ---------------- Flash attention (2-phase gload_lds pipeline) ----------------
// block 256 (4 waves x 32 q-rows = 128 rows), grid = 4n * 50 it * jsplit.
__global__ __launch_bounds__(256, 3) void attn_kernel(
    const u16* __restrict__ QTc, const u16* __restrict__ KT, const u16* __restrict__ Vw,
    float* __restrict__ out,
    float* __restrict__ Opart, float* __restrict__ Mpart, float* __restrict__ Lpart,
    int jsplit, int NT)
{
    __shared__ char lds[49152];        // 2 x (K 8KB + V 16KB)

    const int tid  = threadIdx.x;
    const int lane = tid & 63;
    const int w    = tid >> 6;
    const int l31  = lane & 31;
    const int h    = lane >> 5;

    const int per_n = 50 * jsplit;
    const int n    = blockIdx.x / per_n;
    const int rem  = blockIdx.x - n * per_n;
    const int it   = rem / jsplit;
    const int js   = rem - it * jsplit;
    const int i0   = it * 128;
    const int jt0  = js * NT;

    const int row = i0 + w * 32 + l31;

    // Q B-frags from c-major QTc (once per block): ch = kc*16 + h*8 + e
    const u16* qb = QTc + (size_t)n * 64 * HW + row;
    bf16x8 qf[4];
    #pragma unroll
    for (int kc = 0; kc < 4; ++kc) {
        union { u16 s[8]; bf16x8 v; } uu;
        #pragma unroll
        for (int e = 0; e < 8; ++e)
            uu.s[e] = qb[(size_t)(kc * 16 + h * 8 + e) * HW];
        qf[kc] = uu.v;
    }

    const char* Kg = (const char*)(KT + (size_t)n * HW * 64);    // [p][64] 128B rows
    const char* Vg = (const char*)(Vw + (size_t)n * 128 * HW);   // [c][HW] 12800B rows

    // stage: 6 global_load_lds per wave; LDS dest = wave-uniform base (lane x16
    // scatter implicit); source pre-swizzled with the same XOR used on reads.
    auto stage = [&](int buf, int jt) {
        char* B = lds + buf * 24576;
        #pragma unroll
        for (int q = 0; q < 2; ++q) {
            int abase = (2 * w + q) * 1024;
            int a = abase + lane * 16;
            int r = a >> 7;
            gload_lds16(Kg + (size_t)jt * 8192 + (size_t)(a ^ ((r & 7) << 4)), B + abase);
        }
        #pragma unroll
        for (int q = 0; q < 4; ++q) {
            int abase = (4 * w + q) * 1024;
            int a = abase + lane * 16;
            int c = a >> 7, off = a & 127;
            gload_lds16(Vg + (size_t)c * 12800 + (size_t)jt * 128 + (size_t)(off ^ ((c & 7) << 4)),
                        B + 8192 + abase);
        }
    };

    f32x16 o_acc[4] = {};
    float m = -3e38f, lsum = 0.f;

    auto compute = [&](int buf) {
        char* Klds = lds + buf * 24576;
        char* Vlds = Klds + 8192;

        // ---- S^T = K * Q ----
        f32x16 s0 = {}, s1 = {};
        #pragma unroll
        for (int kc = 0; kc < 4; ++kc) {
            const int cidx = (2 * kc + h) * 16;
            bf16x8 kf0 = *(const bf16x8*)(Klds + l31 * 128        + (cidx ^ ((l31 & 7) << 4)));
            bf16x8 kf1 = *(const bf16x8*)(Klds + (32 + l31) * 128 + (cidx ^ ((l31 & 7) << 4)));
            s0 = __builtin_amdgcn_mfma_f32_32x32x16_bf16(kf0, qf[kc], s0, 0, 0, 0);
            s1 = __builtin_amdgcn_mfma_f32_32x32x16_bf16(kf1, qf[kc], s1, 0, 0, 0);
        }

        // ---- in-lane online softmax (lane owns q-row l31; halves share via xor-32) ----
        float rmax = s0[0];
        #pragma unroll
        for (int r = 1; r < 16; ++r) rmax = fmaxf(rmax, s0[r]);
        #pragma unroll
        for (int r = 0; r < 16; ++r) rmax = fmaxf(rmax, s1[r]);
        rmax = fmaxf(rmax, __shfl_xor(rmax, 32, 64));

        if (__any(rmax > m + DEFER_THR)) {
            float mnew = fmaxf(m, rmax);
            float alpha = exp2f(m - mnew);
            lsum *= alpha;
            #pragma unroll
            for (int cb = 0; cb < 4; ++cb)
                #pragma unroll
                for (int r = 0; r < 16; ++r) o_acc[cb][r] *= alpha;
            m = mnew;
        }

        float rs = 0.f;
        #pragma unroll
        for (int r = 0; r < 16; ++r) { s0[r] = exp2f(s0[r] - m); rs += s0[r]; }
        #pragma unroll
        for (int r = 0; r < 16; ++r) { s1[r] = exp2f(s1[r] - m); rs += s1[r]; }
        rs += __shfl_xor(rs, 32, 64);
        lsum += rs;

        // ---- pack P^T B-frags in-register (cvt_pk + permlane32_swap) ----
        bf16x8 pf[4];
        #pragma unroll
        for (int kb = 0; kb < 4; ++kb) {
            f32x16 sv = (kb < 2) ? s0 : s1;
            const int b = (kb & 1) * 8;
            u32 w0 = cvt_pk_bf16(sv[b + 0], sv[b + 1]);
            u32 w1 = cvt_pk_bf16(sv[b + 2], sv[b + 3]);
            u32 w2 = cvt_pk_bf16(sv[b + 4], sv[b + 5]);
            u32 w3 = cvt_pk_bf16(sv[b + 6], sv[b + 7]);
            asm("v_permlane32_swap_b32 %0, %1" : "+v"(w0), "+v"(w2));
            asm("v_permlane32_swap_b32 %0, %1" : "+v"(w1), "+v"(w3));
            union { u32 u[4]; bf16x8 v; } uu;
            uu.u[0] = w0; uu.u[1] = w1; uu.u[2] = w2; uu.u[3] = w3;
            pf[kb] = uu.v;
        }

        // ---- O^T += V * P^T ----
        #pragma unroll
        for (int kb = 0; kb < 4; ++kb) {
            const int jidx = (2 * kb + h) * 16;
            #pragma unroll
            for (int cb = 0; cb < 4; ++cb) {
                const int crow = cb * 32 + l31;
                bf16x8 vf = *(const bf16x8*)(Vlds + crow * 128 + (jidx ^ ((crow & 7) << 4)));
                o_acc[cb] = __builtin_amdgcn_mfma_f32_32x32x16_bf16(vf, pf[kb], o_acc[cb], 0, 0, 0);
            }
        }
    };

    // ---- 2-phase pipeline: stage(t+1) issued before compute(t); the
    // __syncthreads() vmcnt drain lands after ~full compute phase of cover ----
    stage(0, jt0);
    __syncthreads();
    int t = 0;
    for (; t + 2 <= NT; t += 2) {
        stage(1, jt0 + t + 1);
        compute(0);
        __syncthreads();
        if (t + 2 < NT) stage(0, jt0 + t + 2);
        compute(1);
        __syncthreads();
    }
    if (t < NT) compute(0);

    // ---- epilogue: i = l31 lane-local -> coalesced stores, no shuffles ----
    if (Opart != nullptr) {
        float* Ob = Opart + (size_t)(js * 4 + n) * 128 * HW + row;
        #pragma unroll
        for (int cb = 0; cb < 4; ++cb)
            #pragma unroll
            for (int r = 0; r < 16; ++r) {
                int c = cb * 32 + (r & 3) + 8 * (r >> 2) + 4 * h;
                Ob[(size_t)c * HW] = o_acc[cb][r];
            }
        if (h == 0) {
            Mpart[(size_t)(js * 4 + n) * HW + row] = m;
            Lpart[(size_t)(js * 4 + n) * HW + row] = lsum;
        }
    } else {
        float inv = 1.f / lsum;
        float* ob = out + (size_t)n * 128 * HW + row;
        #pragma unroll
        for (int cb = 0; cb < 4; ++cb)
            #pragma unroll
            for (int r = 0; r < 16; ++r) {
                int c = cb * 32 + (r & 3) + 8 * (r >> 2) + 4 * h;
                ob[(size_t)c * HW] = o_acc[cb][r] * inv;
            }
    }
}

// ---------------- Combine kernel (jsplit = 4) ----------------
__global__ __launch_bounds__(256) void combine_kernel(
    const float* __restrict__ Opart, const float* __restrict__ Mpart,
    const float* __restrict__ Lpart, float* __restrict__ out)
{
    const int b = blockIdx.x;
    const int n = b / 100;
    const int rem = b - n * 100;
    const int cq = rem / 25;
    const int ic = rem - cq * 25;
    const int i = ic * 256 + threadIdx.x;

    float mj[4], wj[4];
    #pragma unroll
    for (int js = 0; js < 4; ++js) mj[js] = Mpart[(size_t)(js * 4 + n) * HW + i];
    float M = fmaxf(fmaxf(mj[0], mj[1]), fmaxf(mj[2], mj[3]));
    float L = 0.f;
    #pragma unroll
    for (int js = 0; js < 4; ++js) {
        wj[js] = exp2f(mj[js] - M);
        L += Lpart[(size_t)(js * 4 + n) * HW + i] * wj[js];
    }
    const float inv = 1.f / L;

    for (int c = cq * 32; c < cq * 32 + 32; ++c) {
        float acc = 0.f;
        #pragma unroll
        for (int js = 0; js < 4; ++js)
            acc += Opart[((size_t)(js * 4 + n) * 128 + c) * HW + i] * wj[js];
        out[((size_t)n * 128 + c) * HW + i] = acc * inv;
    }
}

extern "C" void kernel_launch(void* const* d_in, const int* in_sizes, int n_in,
                              void* d_out, int out_size, void* d_ws, size_t ws_size,
                              hipStream_t stream) {
    const float* x  = (const float*)d_in[0];
    const float* Wq = (const float*)d_in[1];
    const float* bq = (const float*)d_in[2];
    const float* aq = (const float*)d_in[3];
    const float* Wk = (const float*)d_in[4];
    const float* bk = (const float*)d_in[5];
    const float* ak = (const float*)d_in[6];
    const float* Wv = (const float*)d_in[7];
    const float* bv = (const float*)d_in[8];
    const float* av = (const float*)d_in[9];

    char* wsp = (char*)d_ws;
    u16* QTc = (u16*)wsp;                          // [4][64][6400] bf16  = 3,276,800 B
    u16* KT  = (u16*)(wsp + 3276800);              // [4][6400][64] bf16  = 3,276,800 B
    u16* Vw  = (u16*)(wsp + 6553600);              // [4][128][6400] bf16 = 6,553,600 B
    const size_t base = 13107200;
    float* Opart = (float*)(wsp + base);                        // 16*128*6400*4 = 52,428,800 B
    float* Mpart = (float*)(wsp + base + 52428800);             // 409,600 B
    float* Lpart = (float*)(wsp + base + 52428800 + 409600);    // 409,600 B
    const size_t need = base + 52428800 + 2 * 409600;

    proj_kernel<<<dim3(400), 256, 0, stream>>>(x, Wq, bq, aq, Wk, bk, ak, Wv, bv, av,
                                               QTc, KT, Vw);

    if (ws_size >= need) {
        attn_kernel<<<dim3(4 * 50 * 4), 256, 0, stream>>>(QTc, KT, Vw, (float*)d_out,
                                                          Opart, Mpart, Lpart, 4, 25);
        combine_kernel<<<dim3(400), 256, 0, stream>>>(Opart, Mpart, Lpart, (float*)d_out);
    } else {
        attn_kernel<<<dim3(200), 256, 0, stream>>>(QTc, KT, Vw, (float*)d_out,
                                                   nullptr, nullptr, nullptr, 1, 100);
    }
}